// Round 1
// baseline (99.689 us; speedup 1.0000x reference)
//
#include <hip/hip_runtime.h>
#include <math.h>

// GTNormalLoss: kNN(k=10) PCA normals + cosine loss vs gt, mean over 8x4096 points.
// Round 1: brute-force O(N^2) distance scan per batch from LDS, packed-u32 top-10
// via unconditional v_med3_u32 sift, analytic 3x3 eigensolve in f64.

#define NPTS   4096
#define KNN    10
#define QPB    128      // queries per block
#define THREADS 256     // 2 threads per query
#define HALFC  2048     // candidates per thread
#define NBLOCKS 256     // 8 batches * 32 chunks

__device__ __forceinline__ unsigned int umed3(unsigned int a, unsigned int b, unsigned int c) {
    unsigned int r;
    asm("v_med3_u32 %0, %1, %2, %3" : "=v"(r) : "v"(a), "v"(b), "v"(c));
    return r;
}

// insert key into ascending sorted nd[0..9], dropping old max; all static indexing.
__device__ __forceinline__ void sift(unsigned int nd[KNN], unsigned int key) {
#pragma unroll
    for (int t = KNN - 1; t >= 1; --t)
        nd[t] = umed3(key, nd[t - 1], nd[t]);
    nd[0] = nd[0] < key ? nd[0] : key;
}

__global__ __launch_bounds__(THREADS) void gtnl_main(
    const float* __restrict__ pred, const float* __restrict__ gt,
    float* __restrict__ partial)
{
    __shared__ float4 pts[NPTS];                 // 64 KB: x,y,z,|p|^2
    __shared__ unsigned int mbuf[QPB][KNN];      // partner top-10 lists
    __shared__ float rbuf[THREADS];

    const int tid = threadIdx.x;
    const int b   = blockIdx.x >> 5;             // batch
    const int qc  = blockIdx.x & 31;             // query chunk
    const int ql  = tid & (QPB - 1);             // query within chunk
    const int hlf = tid >> 7;                    // which candidate half
    const int qi  = qc * QPB + ql;               // query index in batch

    // stage batch points into LDS with precomputed squared norm
    const float* src = pred + (size_t)b * NPTS * 3;
    for (int p = tid; p < NPTS; p += THREADS) {
        float x = src[3 * p + 0];
        float y = src[3 * p + 1];
        float z = src[3 * p + 2];
        float w = fmaf(x, x, fmaf(y, y, z * z));
        pts[p] = make_float4(x, y, z, w);
    }
    __syncthreads();

    const float4 q = pts[qi];

    unsigned int nd[KNN];
#pragma unroll
    for (int t = 0; t < KNN; ++t) nd[t] = 0xFFFFFFFFu;

    const int j0 = hlf * HALFC;
#pragma unroll 4
    for (int j = j0; j < j0 + HALFC; ++j) {
        float4 c = pts[j];                              // broadcast ds_read_b128
        float dp = fmaf(q.x, c.x, fmaf(q.y, c.y, q.z * c.z));
        float d  = fmaf(-2.0f, dp, q.w + c.w);          // same formula as reference
        d = fmaxf(d, 0.0f);                             // self-distance -> exactly 0
        unsigned int key = (__float_as_uint(d) & 0xFFFFF000u) | (unsigned int)j;
        sift(nd, key);
    }

    if (hlf == 1) {
#pragma unroll
        for (int t = 0; t < KNN; ++t) mbuf[ql][t] = nd[t];
    }
    __syncthreads();

    float res = 0.0f;
    if (hlf == 0) {
        // merge partner's 10 into ours -> exact global top-10 (ascending distance)
#pragma unroll
        for (int t = 0; t < KNN; ++t) sift(nd, mbuf[ql][t]);

        // gather neighborhood, mean, covariance (fp32, matching reference)
        float nbx[KNN], nby[KNN], nbz[KNN];
        float sx = 0.f, sy = 0.f, sz = 0.f;
#pragma unroll
        for (int t = 0; t < KNN; ++t) {
            float4 pn = pts[nd[t] & 0xFFFu];
            nbx[t] = pn.x; nby[t] = pn.y; nbz[t] = pn.z;
            sx += pn.x; sy += pn.y; sz += pn.z;
        }
        float mx = sx / 10.0f, my = sy / 10.0f, mz = sz / 10.0f;
        float c00 = 0.f, c01 = 0.f, c02 = 0.f, c11 = 0.f, c12 = 0.f, c22 = 0.f;
#pragma unroll
        for (int t = 0; t < KNN; ++t) {
            float ux = nbx[t] - mx, uy = nby[t] - my, uz = nbz[t] - mz;
            c00 = fmaf(ux, ux, c00);
            c01 = fmaf(ux, uy, c01);
            c02 = fmaf(ux, uz, c02);
            c11 = fmaf(uy, uy, c11);
            c12 = fmaf(uy, uz, c12);
            c22 = fmaf(uz, uz, c22);
        }
        double a00 = (double)(c00 / 10.0f), a01 = (double)(c01 / 10.0f);
        double a02 = (double)(c02 / 10.0f), a11 = (double)(c11 / 10.0f);
        double a12 = (double)(c12 / 10.0f), a22 = (double)(c22 / 10.0f);

        // analytic smallest eigenpair of symmetric 3x3 (f64)
        double vx = 1.0, vy = 0.0, vz = 0.0;
        double qd = (a00 + a11 + a22) / 3.0;
        double p1 = a01 * a01 + a02 * a02 + a12 * a12;
        double b00 = a00 - qd, b11 = a11 - qd, b22 = a22 - qd;
        double p2 = b00 * b00 + b11 * b11 + b22 * b22 + 2.0 * p1;
        if (p2 > 1e-300) {
            double p = sqrt(p2 / 6.0);
            double inv = 1.0 / p;
            double m00 = b00 * inv, m01 = a01 * inv, m02 = a02 * inv;
            double m11 = b11 * inv, m12 = a12 * inv, m22 = b22 * inv;
            double detB = m00 * (m11 * m22 - m12 * m12)
                        - m01 * (m01 * m22 - m12 * m02)
                        + m02 * (m01 * m12 - m11 * m02);
            double r = 0.5 * detB;
            r = r < -1.0 ? -1.0 : (r > 1.0 ? 1.0 : r);
            double phi = acos(r) / 3.0;
            double eig0 = qd + 2.0 * p * cos(phi + 2.0943951023931953); // smallest
            // rows of A - eig0*I (symmetric)
            double r0x = a00 - eig0, r0y = a01, r0z = a02;
            double r1y = a11 - eig0, r1z = a12;
            double r2z = a22 - eig0;
            // cross products of row pairs
            double c0x = r0y * r1z - r0z * r1y;
            double c0y = r0z * r0y - r0x * r1z;
            double c0z = r0x * r1y - r0y * r0y;
            double c1x = r0y * r2z - r0z * r1z;
            double c1y = r0z * r0z - r0x * r2z;
            double c1z = r0x * r1z - r0y * r0z;
            double c2x = r1y * r2z - r1z * r1z;
            double c2y = r1z * r0z - r0y * r2z;
            double c2z = r0y * r1z - r1y * r0z;
            double n0 = c0x * c0x + c0y * c0y + c0z * c0z;
            double n1 = c1x * c1x + c1y * c1y + c1z * c1z;
            double n2 = c2x * c2x + c2y * c2y + c2z * c2z;
            double bx, by, bz, bn;
            if (n0 >= n1 && n0 >= n2) { bx = c0x; by = c0y; bz = c0z; bn = n0; }
            else if (n1 >= n2)        { bx = c1x; by = c1y; bz = c1z; bn = n1; }
            else                      { bx = c2x; by = c2y; bz = c2z; bn = n2; }
            if (bn > 1e-300) {
                double s = 1.0 / sqrt(bn);
                vx = bx * s; vy = by * s; vz = bz * s;
            }
        }
        float nx = (float)vx, ny = (float)vy, nz = (float)vz;

        const float* g = gt + ((size_t)b * NPTS + qi) * 3;
        float gx = g[0], gy = g[1], gz = g[2];
        float dotg = nx * gx + ny * gy + nz * gz;
        float na = sqrtf(nx * nx + ny * ny + nz * nz);
        float gn = sqrtf(gx * gx + gy * gy + gz * gz);
        float cs = dotg / (fmaxf(na, 1e-8f) * fmaxf(gn, 1e-8f));
        res = 1.0f - cs;
    }

    // deterministic block reduction
    rbuf[tid] = res;
    __syncthreads();
    for (int s = THREADS / 2; s > 0; s >>= 1) {
        if (tid < s) rbuf[tid] += rbuf[tid + s];
        __syncthreads();
    }
    if (tid == 0) partial[blockIdx.x] = rbuf[0];
}

__global__ __launch_bounds__(NBLOCKS) void gtnl_reduce(
    const float* __restrict__ partial, float* __restrict__ out)
{
    __shared__ float s[NBLOCKS];
    const int tid = threadIdx.x;
    s[tid] = partial[tid];
    __syncthreads();
    for (int k = NBLOCKS / 2; k > 0; k >>= 1) {
        if (tid < k) s[tid] += s[tid + k];
        __syncthreads();
    }
    if (tid == 0) out[0] = s[0] / 32768.0f;
}

extern "C" void kernel_launch(void* const* d_in, const int* in_sizes, int n_in,
                              void* d_out, int out_size, void* d_ws, size_t ws_size,
                              hipStream_t stream) {
    const float* pred = (const float*)d_in[0];
    const float* gt   = (const float*)d_in[1];
    float* out        = (float*)d_out;
    float* partial    = (float*)d_ws;   // 256 floats

    gtnl_main<<<NBLOCKS, THREADS, 0, stream>>>(pred, gt, partial);
    gtnl_reduce<<<1, NBLOCKS, 0, stream>>>(partial, out);
}

// Round 2
// 71.676 us; speedup vs baseline: 1.3908x; 1.3908x over previous
//
#include <hip/hip_runtime.h>
#include <math.h>

// GTNormalLoss: kNN(k=10) PCA normals + cosine loss vs gt, mean over 8x4096 points.
// Round 2: 4 threads/query (1024 candidates each), 512 blocks -> 2 blocks/CU,
// 8 waves/CU (2 waves/SIMD) to hide VALU/LDS stalls. Same exact math as R1.

#define NPTS    4096
#define KNN     10
#define QPB     64      // queries per block
#define THREADS 256     // 4 threads per query (one wave per candidate-quarter)
#define QUARTC  1024    // candidates per thread
#define NBLOCKS 512     // 8 batches * 64 chunks

__device__ __forceinline__ unsigned int umed3(unsigned int a, unsigned int b, unsigned int c) {
    unsigned int r;
    asm("v_med3_u32 %0, %1, %2, %3" : "=v"(r) : "v"(a), "v"(b), "v"(c));
    return r;
}

// insert key into ascending sorted nd[0..9], dropping old max; all static indexing.
__device__ __forceinline__ void sift(unsigned int nd[KNN], unsigned int key) {
#pragma unroll
    for (int t = KNN - 1; t >= 1; --t)
        nd[t] = umed3(key, nd[t - 1], nd[t]);
    nd[0] = nd[0] < key ? nd[0] : key;
}

__global__ __launch_bounds__(THREADS) void gtnl_main(
    const float* __restrict__ pred, const float* __restrict__ gt,
    float* __restrict__ partial)
{
    __shared__ float4 pts[NPTS];                    // 64 KB: x,y,z,|p|^2
    __shared__ unsigned int mbuf[QPB][3][KNN];      // partner top-10 lists (subs 1..3)
    __shared__ float rbuf[THREADS];

    const int tid = threadIdx.x;
    const int b   = blockIdx.x >> 6;                // batch
    const int qc  = blockIdx.x & 63;                // query chunk
    const int ql  = tid & (QPB - 1);                // query within chunk
    const int sub = tid >> 6;                       // wave index = candidate quarter
    const int qi  = qc * QPB + ql;                  // query index in batch

    // stage batch points into LDS with precomputed squared norm
    const float* src = pred + (size_t)b * NPTS * 3;
    for (int p = tid; p < NPTS; p += THREADS) {
        float x = src[3 * p + 0];
        float y = src[3 * p + 1];
        float z = src[3 * p + 2];
        float w = fmaf(x, x, fmaf(y, y, z * z));
        pts[p] = make_float4(x, y, z, w);
    }
    __syncthreads();

    const float4 q = pts[qi];

    unsigned int nd[KNN];
#pragma unroll
    for (int t = 0; t < KNN; ++t) nd[t] = 0xFFFFFFFFu;

    const int j0 = sub * QUARTC;
#pragma unroll 8
    for (int j = j0; j < j0 + QUARTC; ++j) {
        float4 c = pts[j];                              // broadcast ds_read_b128
        float dp = fmaf(q.x, c.x, fmaf(q.y, c.y, q.z * c.z));
        float d  = fmaf(-2.0f, dp, q.w + c.w);          // same formula as reference
        d = fmaxf(d, 0.0f);                             // self-distance -> exactly 0
        unsigned int key = (__float_as_uint(d) & 0xFFFFF000u) | (unsigned int)j;
        sift(nd, key);
    }

    if (sub != 0) {
#pragma unroll
        for (int t = 0; t < KNN; ++t) mbuf[ql][sub - 1][t] = nd[t];
    }
    __syncthreads();

    float res = 0.0f;
    if (sub == 0) {
        // merge partners' 30 keys -> exact global top-10 (ascending distance)
#pragma unroll
        for (int s = 0; s < 3; ++s)
#pragma unroll
            for (int t = 0; t < KNN; ++t) sift(nd, mbuf[ql][s][t]);

        // gather neighborhood, mean, covariance (fp32, matching reference)
        float nbx[KNN], nby[KNN], nbz[KNN];
        float sx = 0.f, sy = 0.f, sz = 0.f;
#pragma unroll
        for (int t = 0; t < KNN; ++t) {
            float4 pn = pts[nd[t] & 0xFFFu];
            nbx[t] = pn.x; nby[t] = pn.y; nbz[t] = pn.z;
            sx += pn.x; sy += pn.y; sz += pn.z;
        }
        float mx = sx / 10.0f, my = sy / 10.0f, mz = sz / 10.0f;
        float c00 = 0.f, c01 = 0.f, c02 = 0.f, c11 = 0.f, c12 = 0.f, c22 = 0.f;
#pragma unroll
        for (int t = 0; t < KNN; ++t) {
            float ux = nbx[t] - mx, uy = nby[t] - my, uz = nbz[t] - mz;
            c00 = fmaf(ux, ux, c00);
            c01 = fmaf(ux, uy, c01);
            c02 = fmaf(ux, uz, c02);
            c11 = fmaf(uy, uy, c11);
            c12 = fmaf(uy, uz, c12);
            c22 = fmaf(uz, uz, c22);
        }
        double a00 = (double)(c00 / 10.0f), a01 = (double)(c01 / 10.0f);
        double a02 = (double)(c02 / 10.0f), a11 = (double)(c11 / 10.0f);
        double a12 = (double)(c12 / 10.0f), a22 = (double)(c22 / 10.0f);

        // analytic smallest eigenpair of symmetric 3x3 (f64)
        double vx = 1.0, vy = 0.0, vz = 0.0;
        double qd = (a00 + a11 + a22) / 3.0;
        double p1 = a01 * a01 + a02 * a02 + a12 * a12;
        double b00 = a00 - qd, b11 = a11 - qd, b22 = a22 - qd;
        double p2 = b00 * b00 + b11 * b11 + b22 * b22 + 2.0 * p1;
        if (p2 > 1e-300) {
            double p = sqrt(p2 / 6.0);
            double inv = 1.0 / p;
            double m00 = b00 * inv, m01 = a01 * inv, m02 = a02 * inv;
            double m11 = b11 * inv, m12 = a12 * inv, m22 = b22 * inv;
            double detB = m00 * (m11 * m22 - m12 * m12)
                        - m01 * (m01 * m22 - m12 * m02)
                        + m02 * (m01 * m12 - m11 * m02);
            double r = 0.5 * detB;
            r = r < -1.0 ? -1.0 : (r > 1.0 ? 1.0 : r);
            double phi = acos(r) / 3.0;
            double eig0 = qd + 2.0 * p * cos(phi + 2.0943951023931953); // smallest
            // rows of A - eig0*I (symmetric)
            double r0x = a00 - eig0, r0y = a01, r0z = a02;
            double r1y = a11 - eig0, r1z = a12;
            double r2z = a22 - eig0;
            // cross products of row pairs
            double c0x = r0y * r1z - r0z * r1y;
            double c0y = r0z * r0y - r0x * r1z;
            double c0z = r0x * r1y - r0y * r0y;
            double c1x = r0y * r2z - r0z * r1z;
            double c1y = r0z * r0z - r0x * r2z;
            double c1z = r0x * r1z - r0y * r0z;
            double c2x = r1y * r2z - r1z * r1z;
            double c2y = r1z * r0z - r0y * r2z;
            double c2z = r0y * r1z - r1y * r0z;
            double n0 = c0x * c0x + c0y * c0y + c0z * c0z;
            double n1 = c1x * c1x + c1y * c1y + c1z * c1z;
            double n2 = c2x * c2x + c2y * c2y + c2z * c2z;
            double bx, by, bz, bn;
            if (n0 >= n1 && n0 >= n2) { bx = c0x; by = c0y; bz = c0z; bn = n0; }
            else if (n1 >= n2)        { bx = c1x; by = c1y; bz = c1z; bn = n1; }
            else                      { bx = c2x; by = c2y; bz = c2z; bn = n2; }
            if (bn > 1e-300) {
                double s = 1.0 / sqrt(bn);
                vx = bx * s; vy = by * s; vz = bz * s;
            }
        }
        float nx = (float)vx, ny = (float)vy, nz = (float)vz;

        const float* g = gt + ((size_t)b * NPTS + qi) * 3;
        float gx = g[0], gy = g[1], gz = g[2];
        float dotg = nx * gx + ny * gy + nz * gz;
        float na = sqrtf(nx * nx + ny * ny + nz * nz);
        float gn = sqrtf(gx * gx + gy * gy + gz * gz);
        float cs = dotg / (fmaxf(na, 1e-8f) * fmaxf(gn, 1e-8f));
        res = 1.0f - cs;
    }

    // deterministic block reduction
    rbuf[tid] = res;
    __syncthreads();
    for (int s = THREADS / 2; s > 0; s >>= 1) {
        if (tid < s) rbuf[tid] += rbuf[tid + s];
        __syncthreads();
    }
    if (tid == 0) partial[blockIdx.x] = rbuf[0];
}

__global__ __launch_bounds__(NBLOCKS) void gtnl_reduce(
    const float* __restrict__ partial, float* __restrict__ out)
{
    __shared__ float s[NBLOCKS];
    const int tid = threadIdx.x;
    s[tid] = partial[tid];
    __syncthreads();
    for (int k = NBLOCKS / 2; k > 0; k >>= 1) {
        if (tid < k) s[tid] += s[tid + k];
        __syncthreads();
    }
    if (tid == 0) out[0] = s[0] / 32768.0f;
}

extern "C" void kernel_launch(void* const* d_in, const int* in_sizes, int n_in,
                              void* d_out, int out_size, void* d_ws, size_t ws_size,
                              hipStream_t stream) {
    const float* pred = (const float*)d_in[0];
    const float* gt   = (const float*)d_in[1];
    float* out        = (float*)d_out;
    float* partial    = (float*)d_ws;   // 512 floats

    gtnl_main<<<NBLOCKS, THREADS, 0, stream>>>(pred, gt, partial);
    gtnl_reduce<<<1, NBLOCKS, 0, stream>>>(partial, out);
}